// Round 3
// baseline (668.459 us; speedup 1.0000x reference)
//
#include <hip/hip_runtime.h>
#include <hip/hip_bf16.h>

static constexpr int Hd = 768;    // H
static constexpr int H2 = 1536;   // 2H
static constexpr int Cn = 64;     // C (labels)

typedef __attribute__((ext_vector_type(8))) short short8;
typedef __attribute__((ext_vector_type(4))) float f32x4;

__device__ inline unsigned int f2bf2(float a, float b) {
    __hip_bfloat162 h = __float22bfloat162_rn(float2{a, b});
    return *reinterpret_cast<unsigned int*>(&h);
}

__device__ inline void split1(float x, unsigned short& h, unsigned short& l) {
    __hip_bfloat16 hb = __float2bfloat16(x);
    float hf = __bfloat162float(hb);
    __hip_bfloat16 lb_ = __float2bfloat16(x - hf);
    h = *reinterpret_cast<unsigned short*>(&hb);
    l = *reinterpret_cast<unsigned short*>(&lb_);
}

// ---------------- scatter pooling ----------------
__global__ void k_init_widx(int* widx, int Wd) {
    int i = blockIdx.x * 256 + threadIdx.x;
    if (i < Wd) widx[i] = -1;
}

__global__ void k_scatter(const int* __restrict__ wmask, int* widx, int L, int Wd) {
    int i = blockIdx.x * 256 + threadIdx.x;
    if (i < L) {
        int m = wmask[i];
        if (m > 0 && m <= Wd) atomicMax(&widx[m - 1], i);  // last token wins
    }
}

__global__ void k_build_we(const float4* __restrict__ tok, const int* __restrict__ widx,
                           float4* __restrict__ we, int Wd) {
    int i = blockIdx.x * 256 + threadIdx.x;
    const int cols = Hd / 4;
    int w = i / cols, c = i - w * cols;
    if (w >= Wd) return;
    int idx = widx[w];
    we[i] = (idx >= 0) ? tok[idx * cols + c] : float4{0.f, 0.f, 0.f, 0.f};
}

// ---------- transpose + hi/lo bf16 split: T[n][k] = split(W[k][n]) ----------
// grid: (N/64, K/64); ld = N (source row length); Kd = K (output row length)
__global__ __launch_bounds__(256)
void k_tsplit(const float* __restrict__ W, int ld,
              unsigned short* __restrict__ Th, unsigned short* __restrict__ Tl, int Kd) {
    __shared__ float tile[64][65];
    const int n0 = blockIdx.x * 64, k0 = blockIdx.y * 64;
    for (int idx = threadIdx.x; idx < 4096; idx += 256) {
        int kk = idx >> 6, nn = idx & 63;
        tile[kk][nn] = W[(size_t)(k0 + kk) * ld + n0 + nn];
    }
    __syncthreads();
    for (int idx = threadIdx.x; idx < 4096; idx += 256) {
        int nn = idx >> 6, kk = idx & 63;
        unsigned short h, l;
        split1(tile[kk][nn], h, l);
        size_t o = (size_t)(n0 + nn) * Kd + k0 + kk;
        Th[o] = h;
        Tl[o] = l;
    }
}

// ---------- row-major hi/lo split (no transpose), float4 per thread ----------
__global__ __launch_bounds__(256)
void k_split(const float* __restrict__ x, int lda, int cols,
             unsigned short* __restrict__ h, unsigned short* __restrict__ l, int n4) {
    int i = blockIdx.x * 256 + threadIdx.x;
    if (i >= n4) return;
    int c4 = cols >> 2;
    int row = i / c4, cc = (i - row * c4) * 4;
    float4 v = *(const float4*)&x[(size_t)row * lda + cc];
    unsigned short hh[4], ll[4];
    split1(v.x, hh[0], ll[0]);
    split1(v.y, hh[1], ll[1]);
    split1(v.z, hh[2], ll[2]);
    split1(v.w, hh[3], ll[3]);
    size_t o = (size_t)row * cols + cc;
    *(ushort4*)&h[o] = ushort4{hh[0], hh[1], hh[2], hh[3]};
    *(ushort4*)&l[o] = ushort4{ll[0], ll[1], ll[2], ll[3]};
}

// ---------- split-bf16 MFMA GEMM: C = (Ah+Al)(Bh+Bl) + bias ----------
// A pre-split [M][K] bf16 hi/lo; B pre-split+transposed [N][K] bf16 hi/lo.
// 64x64 tile, 4 waves each 32x32 (2x2 of 16x16), barrier-free direct loads.
__global__ __launch_bounds__(256)
void k_gemm_sp(const unsigned short* __restrict__ Ah, const unsigned short* __restrict__ Al,
               const unsigned short* __restrict__ BhT, const unsigned short* __restrict__ BlT,
               const float* __restrict__ bias, float* __restrict__ C, int ldc, int K) {
    const int tid = threadIdx.x;
    const int wave = tid >> 6, lane = tid & 63;
    const int quad = lane >> 4, l15 = lane & 15;
    const int wm = wave & 1, wn = wave >> 1;
    const int m0 = blockIdx.y * 64, n0 = blockIdx.x * 64;

    f32x4 acc[2][2];
#pragma unroll
    for (int a = 0; a < 2; ++a)
#pragma unroll
        for (int b = 0; b < 2; ++b) acc[a][b] = (f32x4){0.f, 0.f, 0.f, 0.f};

    for (int k0 = 0; k0 < K; k0 += 32) {
        const int kq = k0 + quad * 8;
        short8 ah[2], al[2], bh[2], bl[2];
#pragma unroll
        for (int mt = 0; mt < 2; ++mt) {
            size_t o = (size_t)(m0 + wm * 32 + mt * 16 + l15) * K + kq;
            ah[mt] = *(const short8*)(Ah + o);
            al[mt] = *(const short8*)(Al + o);
        }
#pragma unroll
        for (int nt = 0; nt < 2; ++nt) {
            size_t o = (size_t)(n0 + wn * 32 + nt * 16 + l15) * K + kq;
            bh[nt] = *(const short8*)(BhT + o);
            bl[nt] = *(const short8*)(BlT + o);
        }
#pragma unroll
        for (int mt = 0; mt < 2; ++mt)
#pragma unroll
            for (int nt = 0; nt < 2; ++nt) {
                acc[mt][nt] = __builtin_amdgcn_mfma_f32_16x16x32_bf16(al[mt], bh[nt], acc[mt][nt], 0, 0, 0);
                acc[mt][nt] = __builtin_amdgcn_mfma_f32_16x16x32_bf16(ah[mt], bl[nt], acc[mt][nt], 0, 0, 0);
                acc[mt][nt] = __builtin_amdgcn_mfma_f32_16x16x32_bf16(ah[mt], bh[nt], acc[mt][nt], 0, 0, 0);
            }
    }
#pragma unroll
    for (int mt = 0; mt < 2; ++mt)
#pragma unroll
        for (int nt = 0; nt < 2; ++nt) {
            int cidx = n0 + wn * 32 + nt * 16 + l15;
            float bb = bias ? bias[cidx] : 0.f;
#pragma unroll
            for (int reg = 0; reg < 4; ++reg) {
                int r = m0 + wm * 32 + mt * 16 + quad * 4 + reg;
                C[(size_t)r * ldc + cidx] = acc[mt][nt][reg] + bb;
            }
        }
}

// ---------------- barrier-free MFMA main kernel ----------------
// Block: 128 rows ((w0,c0..63),(w1,c0..63)) x j in 6 chunks of 128.
// A-frag built in regs: af[i] = bf16(t1[w,kq+i]*lb1[c,kq+i]); B-frag = direct
// short8 from W1ct[j][k]. No LDS / no barriers in the K-loop.
__global__ __launch_bounds__(256, 2)
void k_mfma(const float* __restrict__ t,             // (Wd,1536) f32
            const float* __restrict__ lb,            // (64,1536) f32
            const unsigned short* __restrict__ W1ct, // (768,768) bf16 [j][k]
            const float* __restrict__ Aw,            // (Wd,768) f32
            const float* __restrict__ Bc,            // (64,768) f32 (includes b1)
            const float* __restrict__ W2,            // (768,3)
            const float* __restrict__ b2,            // (3,)
            float* __restrict__ out) {               // (Wd,64,3)
    __shared__ float W2s[Hd * 3];
    __shared__ float sred[128 * 3];

    const int tid = threadIdx.x;
    const int wave = tid >> 6, lane = tid & 63;
    const int quad = lane >> 4, l15 = lane & 15;
    const int mhalf = wave >> 1, nhalf = wave & 1;
    const int wb = blockIdx.x;

    for (int i = tid; i < Hd * 3; i += 256) W2s[i] = W2[i];
    for (int i = tid; i < 128 * 3; i += 256) sred[i] = 0.f;
    __syncthreads();

    const int w_wave = wb * 2 + mhalf;
    const float* t1p = t + (size_t)w_wave * H2 + Hd;

    float sacc[4][4][3] = {};

    for (int chunk = 0; chunk < 6; ++chunk) {
        const int j0 = chunk * 128;
        f32x4 acc[4][4];
#pragma unroll
        for (int mt = 0; mt < 4; ++mt)
#pragma unroll
            for (int nt = 0; nt < 4; ++nt) acc[mt][nt] = (f32x4){0.f, 0.f, 0.f, 0.f};

        for (int k0 = 0; k0 < Hd; k0 += 32) {
            const int kq = k0 + quad * 8;
            float4 ta = *(const float4*)(t1p + kq);
            float4 tb = *(const float4*)(t1p + kq + 4);
            short8 af[4], bfr[4];
#pragma unroll
            for (int mt = 0; mt < 4; ++mt) {
                const float* lp = lb + (size_t)(mt * 16 + l15) * H2 + Hd + kq;
                float4 la = *(const float4*)lp;
                float4 lc = *(const float4*)(lp + 4);
                union { unsigned int u[4]; short8 s; } o;
                o.u[0] = f2bf2(ta.x * la.x, ta.y * la.y);
                o.u[1] = f2bf2(ta.z * la.z, ta.w * la.w);
                o.u[2] = f2bf2(tb.x * lc.x, tb.y * lc.y);
                o.u[3] = f2bf2(tb.z * lc.z, tb.w * lc.w);
                af[mt] = o.s;
            }
#pragma unroll
            for (int nt = 0; nt < 4; ++nt) {
                const int j = j0 + nhalf * 64 + nt * 16 + l15;
                bfr[nt] = *(const short8*)(W1ct + (size_t)j * Hd + kq);
            }
#pragma unroll
            for (int mt = 0; mt < 4; ++mt)
#pragma unroll
                for (int nt = 0; nt < 4; ++nt)
                    acc[mt][nt] = __builtin_amdgcn_mfma_f32_16x16x32_bf16(
                        af[mt], bfr[nt], acc[mt][nt], 0, 0, 0);
        }

        // epilogue: h = relu(P + Aw + Bc), sacc += h * W2
#pragma unroll
        for (int nt = 0; nt < 4; ++nt) {
            const int jn = j0 + nhalf * 64 + nt * 16 + l15;
            const float aw = Aw[(size_t)w_wave * Hd + jn];
            const float w20 = W2s[jn * 3 + 0], w21 = W2s[jn * 3 + 1], w22 = W2s[jn * 3 + 2];
#pragma unroll
            for (int mt = 0; mt < 4; ++mt)
#pragma unroll
                for (int reg = 0; reg < 4; ++reg) {
                    const int c = mt * 16 + quad * 4 + reg;
                    float h = acc[mt][nt][reg] + aw + Bc[(size_t)c * Hd + jn];
                    h = h > 0.f ? h : 0.f;
                    sacc[mt][reg][0] += h * w20;
                    sacc[mt][reg][1] += h * w21;
                    sacc[mt][reg][2] += h * w22;
                }
        }
    }

    // cross-lane reduce over the 16 j-lanes, combine nhalf waves via LDS
    __syncthreads();
#pragma unroll
    for (int mt = 0; mt < 4; ++mt)
#pragma unroll
        for (int reg = 0; reg < 4; ++reg)
#pragma unroll
            for (int r = 0; r < 3; ++r) {
                float v = sacc[mt][reg][r];
                v += __shfl_xor(v, 1);
                v += __shfl_xor(v, 2);
                v += __shfl_xor(v, 4);
                v += __shfl_xor(v, 8);
                if (l15 == 0)
                    atomicAdd(&sred[(mhalf * 64 + mt * 16 + quad * 4 + reg) * 3 + r], v);
            }
    __syncthreads();
    const float b20 = b2[0], b21 = b2[1], b22 = b2[2];
    for (int i = tid; i < 128 * 3; i += 256) {
        int r = i - (i / 3) * 3;
        float bb = (r == 0) ? b20 : ((r == 1) ? b21 : b22);
        out[(size_t)wb * 384 + i] = sred[i] + bb;
    }
}

extern "C" void kernel_launch(void* const* d_in, const int* in_sizes, int n_in,
                              void* d_out, int out_size, void* d_ws, size_t ws_size,
                              hipStream_t stream) {
    const float* tok    = (const float*)d_in[0];
    const int*   wmask  = (const int*)d_in[1];
    const float* labe   = (const float*)d_in[3];
    const float* W_tok  = (const float*)d_in[4];
    const float* b_tok  = (const float*)d_in[5];
    const float* W_lab  = (const float*)d_in[6];
    const float* b_lab  = (const float*)d_in[7];
    const float* W1     = (const float*)d_in[8];
    const float* b1     = (const float*)d_in[9];
    const float* W2     = (const float*)d_in[10];
    const float* b2     = (const float*)d_in[11];
    float* out = (float*)d_out;

    const int L  = in_sizes[1];
    const int Wd = out_size / (Cn * 3);   // 1024

    typedef unsigned short us;
    char* ws = (char*)d_ws;
    size_t off = 0;
    auto alloc = [&](size_t bytes) { char* p = ws + off; off += (bytes + 255) & ~(size_t)255; return p; };
    int*   widx  = (int*)alloc(4096);
    float* we    = (float*)alloc((size_t)Wd * Hd * 4);
    float* tbuf  = (float*)alloc((size_t)Wd * H2 * 4);
    float* lbuf  = (float*)alloc((size_t)Cn * H2 * 4);
    float* Abuf  = (float*)alloc((size_t)Wd * Hd * 4);
    float* Bbuf  = (float*)alloc((size_t)Cn * Hd * 4);
    us* W1ct  = (us*)alloc((size_t)Hd * Hd * 2);
    us* W1cl  = (us*)alloc((size_t)Hd * Hd * 2);   // unused (hi-only P path)
    us* WtTh  = (us*)alloc((size_t)H2 * Hd * 2);
    us* WtTl  = (us*)alloc((size_t)H2 * Hd * 2);
    us* WlTh  = (us*)alloc((size_t)H2 * Hd * 2);
    us* WlTl  = (us*)alloc((size_t)H2 * Hd * 2);
    us* W1aTh = (us*)alloc((size_t)Hd * Hd * 2);
    us* W1aTl = (us*)alloc((size_t)Hd * Hd * 2);
    us* W1bTh = (us*)alloc((size_t)Hd * Hd * 2);
    us* W1bTl = (us*)alloc((size_t)Hd * Hd * 2);
    us* weh   = (us*)alloc((size_t)Wd * Hd * 2);
    us* wel   = (us*)alloc((size_t)Wd * Hd * 2);
    us* lah   = (us*)alloc((size_t)Cn * Hd * 2);
    us* lal   = (us*)alloc((size_t)Cn * Hd * 2);
    us* t0h   = (us*)alloc((size_t)Wd * Hd * 2);
    us* t0l   = (us*)alloc((size_t)Wd * Hd * 2);
    us* lb0h  = (us*)alloc((size_t)Cn * Hd * 2);
    us* lb0l  = (us*)alloc((size_t)Cn * Hd * 2);

    // 1) scatter pooling
    k_init_widx<<<(Wd + 255) / 256, 256, 0, stream>>>(widx, Wd);
    k_scatter<<<(L + 255) / 256, 256, 0, stream>>>(wmask, widx, L, Wd);
    k_build_we<<<(Wd * (Hd / 4) + 255) / 256, 256, 0, stream>>>((const float4*)tok, widx, (float4*)we, Wd);

    // 2) weight transposes+splits (all [n][k] bf16 hi/lo)
    k_tsplit<<<dim3(H2 / 64, Hd / 64), 256, 0, stream>>>(W_tok, H2, WtTh, WtTl, Hd);
    k_tsplit<<<dim3(H2 / 64, Hd / 64), 256, 0, stream>>>(W_lab, H2, WlTh, WlTl, Hd);
    k_tsplit<<<dim3(Hd / 64, Hd / 64), 256, 0, stream>>>(W1,                      Hd, W1aTh, W1aTl, Hd);
    k_tsplit<<<dim3(Hd / 64, Hd / 64), 256, 0, stream>>>(W1 + (size_t)Hd * Hd,    Hd, W1bTh, W1bTl, Hd);
    k_tsplit<<<dim3(Hd / 64, Hd / 64), 256, 0, stream>>>(W1 + (size_t)2 * Hd * Hd, Hd, W1ct, W1cl, Hd);

    // 3) activation splits
    k_split<<<(Wd * Hd / 4 + 255) / 256, 256, 0, stream>>>(we, Hd, Hd, weh, wel, Wd * Hd / 4);
    k_split<<<(Cn * Hd / 4 + 255) / 256, 256, 0, stream>>>(labe, Hd, Hd, lah, lal, Cn * Hd / 4);

    // 4) t = we @ W_tok + b_tok  (1024 x 1536)
    k_gemm_sp<<<dim3(H2 / 64, Wd / 64), 256, 0, stream>>>(weh, wel, WtTh, WtTl, b_tok, tbuf, H2, Hd);
    // 5) lb = labe @ W_lab + b_lab  (64 x 1536)
    k_gemm_sp<<<dim3(H2 / 64, Cn / 64), 256, 0, stream>>>(lah, lal, WlTh, WlTl, b_lab, lbuf, H2, Hd);

    // 6) split t0 / lb0
    k_split<<<(Wd * Hd / 4 + 255) / 256, 256, 0, stream>>>(tbuf, H2, Hd, t0h, t0l, Wd * Hd / 4);
    k_split<<<(Cn * Hd / 4 + 255) / 256, 256, 0, stream>>>(lbuf, H2, Hd, lb0h, lb0l, Cn * Hd / 4);

    // 7) A = t0 @ W1a  (1024 x 768);  B = lb0 @ W1b + b1  (64 x 768)
    k_gemm_sp<<<dim3(Hd / 64, Wd / 64), 256, 0, stream>>>(t0h, t0l, W1aTh, W1aTl, nullptr, Abuf, Hd, Hd);
    k_gemm_sp<<<dim3(Hd / 64, Cn / 64), 256, 0, stream>>>(lb0h, lb0l, W1bTh, W1bTl, b1, Bbuf, Hd, Hd);

    // 8) barrier-free MFMA P-GEMM + fused epilogue
    k_mfma<<<dim3(Wd / 2), 256, 0, stream>>>(tbuf, lbuf, W1ct, Abuf, Bbuf, W2, b2, out);
}

// Round 4
// 667.332 us; speedup vs baseline: 1.0017x; 1.0017x over previous
//
#include <hip/hip_runtime.h>
#include <hip/hip_bf16.h>

static constexpr int Hd = 768;    // H
static constexpr int H2 = 1536;   // 2H
static constexpr int Cn = 64;     // C (labels)

typedef __attribute__((ext_vector_type(8))) short short8;
typedef __attribute__((ext_vector_type(4))) float f32x4;
typedef unsigned short us;

__device__ inline unsigned int f2bf2(float a, float b) {
    __hip_bfloat162 h = __float22bfloat162_rn(float2{a, b});
    return *reinterpret_cast<unsigned int*>(&h);
}

__device__ inline void split1(float x, us& h, us& l) {
    __hip_bfloat16 hb = __float2bfloat16(x);
    float hf = __bfloat162float(hb);
    __hip_bfloat16 lb_ = __float2bfloat16(x - hf);
    h = *reinterpret_cast<us*>(&hb);
    l = *reinterpret_cast<us*>(&lb_);
}

__device__ inline void gload16(const void* g, void* l) {
    __builtin_amdgcn_global_load_lds(
        (const __attribute__((address_space(1))) unsigned int*)g,
        (__attribute__((address_space(3))) unsigned int*)l, 16, 0, 0);
}

// ---------------- init: widx = -1, out = broadcast b2 ----------------
__global__ void k_init(int* widx, float* out, const float* __restrict__ b2, int Wd, int outN) {
    int i = blockIdx.x * 256 + threadIdx.x;
    if (i < Wd) widx[i] = -1;
    if (i < outN) out[i] = b2[i % 3];
}

__global__ void k_scatter(const int* __restrict__ wmask, int* widx, int L, int Wd) {
    int i = blockIdx.x * 256 + threadIdx.x;
    if (i < L) {
        int m = wmask[i];
        if (m > 0 && m <= Wd) atomicMax(&widx[m - 1], i);  // last token wins
    }
}

// build we directly as hi/lo bf16 split
__global__ void k_build_we_split(const float4* __restrict__ tok, const int* __restrict__ widx,
                                 us* __restrict__ weh, us* __restrict__ wel, int Wd) {
    int i = blockIdx.x * 256 + threadIdx.x;   // over Wd * 192
    if (i >= Wd * 192) return;
    int w = i / 192, c4 = i - w * 192;
    int idx = widx[w];
    float4 v = (idx >= 0) ? tok[idx * 192 + c4] : float4{0.f, 0.f, 0.f, 0.f};
    us hh[4], ll[4];
    split1(v.x, hh[0], ll[0]);
    split1(v.y, hh[1], ll[1]);
    split1(v.z, hh[2], ll[2]);
    split1(v.w, hh[3], ll[3]);
    size_t o = (size_t)w * Hd + c4 * 4;
    *(ushort4*)&weh[o] = ushort4{hh[0], hh[1], hh[2], hh[3]};
    *(ushort4*)&wel[o] = ushort4{ll[0], ll[1], ll[2], ll[3]};
}

// ---------- batched transpose + hi/lo split: T[n][k] = split(W[k][n]) ----------
struct TSArgs {
    const float* src[5];
    us* th[5];
    us* tl[5];
    int ld[5];  // source row length (N of source)
    int N[5];   // output row count
};
__global__ __launch_bounds__(256)
void k_tsplit(TSArgs a) {
    __shared__ float tile[64][65];
    const int z = blockIdx.z;
    const int n0 = blockIdx.x * 64, k0 = blockIdx.y * 64;
    if (n0 >= a.N[z]) return;
    const float* W = a.src[z];
    const int ld = a.ld[z];
    for (int idx = threadIdx.x; idx < 4096; idx += 256) {
        int kk = idx >> 6, nn = idx & 63;
        tile[kk][nn] = W[(size_t)(k0 + kk) * ld + n0 + nn];
    }
    __syncthreads();
    us* Th = a.th[z];
    us* Tl = a.tl[z];
    for (int idx = threadIdx.x; idx < 4096; idx += 256) {
        int nn = idx >> 6, kk = idx & 63;
        us h, l;
        split1(tile[kk][nn], h, l);
        size_t o = (size_t)(n0 + nn) * Hd + k0 + kk;
        Th[o] = h;
        Tl[o] = l;
    }
}

// ---------- row-major hi/lo split ----------
__global__ __launch_bounds__(256)
void k_split(const float* __restrict__ x, int lda, int cols,
             us* __restrict__ h, us* __restrict__ l, int n4) {
    int i = blockIdx.x * 256 + threadIdx.x;
    if (i >= n4) return;
    int c4 = cols >> 2;
    int row = i / c4, cc = (i - row * c4) * 4;
    float4 v = *(const float4*)&x[(size_t)row * lda + cc];
    us hh[4], ll[4];
    split1(v.x, hh[0], ll[0]);
    split1(v.y, hh[1], ll[1]);
    split1(v.z, hh[2], ll[2]);
    split1(v.w, hh[3], ll[3]);
    size_t o = (size_t)row * cols + cc;
    *(ushort4*)&h[o] = ushort4{hh[0], hh[1], hh[2], hh[3]};
    *(ushort4*)&l[o] = ushort4{ll[0], ll[1], ll[2], ll[3]};
}

// ---------- split-bf16 GEMM, LDS double-buffered, K-split partials ----------
// Cpart[z] = (Ah+Al)[:, kslice] @ (Bh+Bl)^T[kslice, :]
__global__ __launch_bounds__(256)
void k_gemm2(const us* __restrict__ Ah, const us* __restrict__ Al,
             const us* __restrict__ BhT, const us* __restrict__ BlT,
             float* __restrict__ Cpart, int M, int N, int K) {
    __shared__ __align__(16) us S[2][4][64 * 32];  // [buf][Ah,Al,Bh,Bl][64r x 32k]
    const int tid = threadIdx.x, wave = tid >> 6, lane = tid & 63;
    const int quad = lane >> 4, l15 = lane & 15;
    const int wm = wave & 1, wn = wave >> 1;
    const int m0 = blockIdx.y * 64, n0 = blockIdx.x * 64;
    const int Ks = K / gridDim.z, kbeg = blockIdx.z * Ks, kend = kbeg + Ks;
    float* C = Cpart + (size_t)blockIdx.z * M * N;

    const int srow = wave * 16 + (lane >> 2), soff = (lane & 3) * 8;
    const size_t gaB = (size_t)(m0 + srow) * K + soff;
    const size_t gbB = (size_t)(n0 + srow) * K + soff;
    const int lo = wave * 16 * 32;

    f32x4 acc[2][2];
#pragma unroll
    for (int a = 0; a < 2; ++a)
#pragma unroll
        for (int b = 0; b < 2; ++b) acc[a][b] = (f32x4){0.f, 0.f, 0.f, 0.f};

    auto stage = [&](int p, int k0) {
        gload16(Ah + gaB + k0, &S[p][0][lo]);
        gload16(Al + gaB + k0, &S[p][1][lo]);
        gload16(BhT + gbB + k0, &S[p][2][lo]);
        gload16(BlT + gbB + k0, &S[p][3][lo]);
    };

    int p = 0;
    stage(0, kbeg);
    for (int k0 = kbeg; k0 < kend; k0 += 32) {
        __syncthreads();                       // drain stage(p) + prior reads
        if (k0 + 32 < kend) stage(p ^ 1, k0 + 32);
        short8 ah[2], al[2], bh[2], bl[2];
#pragma unroll
        for (int mt = 0; mt < 2; ++mt) {
            int off = (wm * 32 + mt * 16 + l15) * 32 + quad * 8;
            ah[mt] = *(const short8*)&S[p][0][off];
            al[mt] = *(const short8*)&S[p][1][off];
        }
#pragma unroll
        for (int nt = 0; nt < 2; ++nt) {
            int off = (wn * 32 + nt * 16 + l15) * 32 + quad * 8;
            bh[nt] = *(const short8*)&S[p][2][off];
            bl[nt] = *(const short8*)&S[p][3][off];
        }
#pragma unroll
        for (int mt = 0; mt < 2; ++mt)
#pragma unroll
            for (int nt = 0; nt < 2; ++nt) {
                acc[mt][nt] = __builtin_amdgcn_mfma_f32_16x16x32_bf16(al[mt], bh[nt], acc[mt][nt], 0, 0, 0);
                acc[mt][nt] = __builtin_amdgcn_mfma_f32_16x16x32_bf16(ah[mt], bl[nt], acc[mt][nt], 0, 0, 0);
                acc[mt][nt] = __builtin_amdgcn_mfma_f32_16x16x32_bf16(ah[mt], bh[nt], acc[mt][nt], 0, 0, 0);
            }
        p ^= 1;
    }
#pragma unroll
    for (int mt = 0; mt < 2; ++mt)
#pragma unroll
        for (int nt = 0; nt < 2; ++nt) {
            int col = n0 + wn * 32 + nt * 16 + l15;
#pragma unroll
            for (int reg = 0; reg < 4; ++reg) {
                int row = m0 + wm * 32 + mt * 16 + quad * 4 + reg;
                C[(size_t)row * N + col] = acc[mt][nt][reg];
            }
        }
}

// ---------- reduce K-split partials + bias; optional f32 out + hi/lo split ----------
__global__ __launch_bounds__(256)
void k_reduce(const float* __restrict__ part, int S, int MN, int N,
              const float* __restrict__ bias, float* __restrict__ outF,
              us* __restrict__ sh, us* __restrict__ sl, int scols) {
    int i = blockIdx.x * 256 + threadIdx.x;
    if (i >= MN) return;
    float v = 0.f;
    for (int s = 0; s < S; ++s) v += part[(size_t)s * MN + i];
    int row = i / N, col = i - row * N;
    if (bias) v += bias[col];
    if (outF) outF[i] = v;
    if (sh && col < scols) {
        us h, l;
        split1(v, h, l);
        size_t o = (size_t)row * scols + col;
        sh[o] = h;
        sl[o] = l;
    }
}

// ---------------- MFMA main kernel v4 ----------------
// grid (512, 3): block = 128 rows (2 words x 64 labels) x 256 j (2 chunks of 128).
// B (W1ct) double-buffered via global_load_lds, 1 barrier/k-step; A built in regs.
// Epilogue per chunk: relu(P+Aw+Bc) contracted with W2 -> LDS sred -> atomicAdd out.
__global__ __launch_bounds__(256)
void k_mfma(const float* __restrict__ t,             // (Wd,1536) f32
            const float* __restrict__ lb,            // (64,1536) f32
            const us* __restrict__ W1ct,             // (768,768) bf16 [j][k]
            const float* __restrict__ Aw,            // (Wd,768) f32
            const float* __restrict__ Bc,            // (64,768) f32 (includes b1)
            const float* __restrict__ W2,            // (768,3) f32
            float* __restrict__ out) {               // (Wd,64,3), pre-biased b2
    __shared__ __align__(16) us Bs[2][128 * 32];     // 16 KB
    __shared__ float sred[128 * 3];

    const int tid = threadIdx.x;
    const int wave = tid >> 6, lane = tid & 63;
    const int quad = lane >> 4, l15 = lane & 15;
    const int mhalf = wave >> 1, nhalf = wave & 1;
    const int wb = blockIdx.x;          // 0..511
    const int jbase = blockIdx.y * 256; // 0,256,512

    for (int i = tid; i < 128 * 3; i += 256) sred[i] = 0.f;

    const int w_wave = wb * 2 + mhalf;
    const float* t1p = t + (size_t)w_wave * H2 + Hd;

    const int srow = wave * 32 + (lane >> 2);
    const int soff = (lane & 3) * 8;

    auto stage = [&](int p, int ch, int k0) {
        const us* g = W1ct + (size_t)(jbase + ch * 128 + srow) * Hd + k0 + soff;
        gload16(g, &Bs[p][(wave * 32) * 32]);
        gload16(g + 16 * Hd, &Bs[p][(wave * 32 + 16) * 32]);
    };

    int p = 0;
    stage(0, 0, 0);
    for (int ch = 0; ch < 2; ++ch) {
        f32x4 acc[4][4];
#pragma unroll
        for (int mt = 0; mt < 4; ++mt)
#pragma unroll
            for (int nt = 0; nt < 4; ++nt) acc[mt][nt] = (f32x4){0.f, 0.f, 0.f, 0.f};

        for (int k0 = 0; k0 < Hd; k0 += 32) {
            __syncthreads();   // drain stage(p); all prior ds_reads done
            int nk = k0 + 32;
            if (nk < Hd) stage(p ^ 1, ch, nk);
            else if (ch == 0) stage(p ^ 1, 1, 0);

            const int kq = k0 + quad * 8;
            float4 ta = *(const float4*)(t1p + kq);
            float4 tb = *(const float4*)(t1p + kq + 4);
            short8 af[4], bfr[4];
#pragma unroll
            for (int mt = 0; mt < 4; ++mt) {
                const float* lp = lb + (size_t)(mt * 16 + l15) * H2 + Hd + kq;
                float4 la = *(const float4*)lp;
                float4 lc = *(const float4*)(lp + 4);
                union { unsigned int u[4]; short8 s; } o;
                o.u[0] = f2bf2(ta.x * la.x, ta.y * la.y);
                o.u[1] = f2bf2(ta.z * la.z, ta.w * la.w);
                o.u[2] = f2bf2(tb.x * lc.x, tb.y * lc.y);
                o.u[3] = f2bf2(tb.z * lc.z, tb.w * lc.w);
                af[mt] = o.s;
            }
#pragma unroll
            for (int nt = 0; nt < 4; ++nt)
                bfr[nt] = *(const short8*)&Bs[p][(nhalf * 64 + nt * 16 + l15) * 32 + quad * 8];
#pragma unroll
            for (int mt = 0; mt < 4; ++mt)
#pragma unroll
                for (int nt = 0; nt < 4; ++nt)
                    acc[mt][nt] = __builtin_amdgcn_mfma_f32_16x16x32_bf16(
                        af[mt], bfr[nt], acc[mt][nt], 0, 0, 0);
            p ^= 1;
        }

        // ---- epilogue chunk ch ----
        float sacc[4][4][3];
#pragma unroll
        for (int a = 0; a < 4; ++a)
#pragma unroll
            for (int b = 0; b < 4; ++b)
#pragma unroll
                for (int r = 0; r < 3; ++r) sacc[a][b][r] = 0.f;
#pragma unroll
        for (int nt = 0; nt < 4; ++nt) {
            const int jn = jbase + ch * 128 + nhalf * 64 + nt * 16 + l15;
            const float aw = Aw[(size_t)w_wave * Hd + jn];
            const float w20 = W2[jn * 3 + 0], w21 = W2[jn * 3 + 1], w22 = W2[jn * 3 + 2];
#pragma unroll
            for (int mt = 0; mt < 4; ++mt)
#pragma unroll
                for (int reg = 0; reg < 4; ++reg) {
                    const int c = mt * 16 + quad * 4 + reg;
                    float h = acc[mt][nt][reg] + aw + Bc[(size_t)c * Hd + jn];
                    h = h > 0.f ? h : 0.f;
                    sacc[mt][reg][0] += h * w20;
                    sacc[mt][reg][1] += h * w21;
                    sacc[mt][reg][2] += h * w22;
                }
        }
#pragma unroll
        for (int mt = 0; mt < 4; ++mt)
#pragma unroll
            for (int reg = 0; reg < 4; ++reg)
#pragma unroll
                for (int r = 0; r < 3; ++r) {
                    float v = sacc[mt][reg][r];
                    v += __shfl_xor(v, 1);
                    v += __shfl_xor(v, 2);
                    v += __shfl_xor(v, 4);
                    v += __shfl_xor(v, 8);
                    if (l15 == 0)
                        atomicAdd(&sred[(mhalf * 64 + mt * 16 + quad * 4 + reg) * 3 + r], v);
                }
    }
    __syncthreads();
    for (int i = tid; i < 128 * 3; i += 256)
        atomicAdd(&out[(size_t)wb * 384 + i], sred[i]);
}

extern "C" void kernel_launch(void* const* d_in, const int* in_sizes, int n_in,
                              void* d_out, int out_size, void* d_ws, size_t ws_size,
                              hipStream_t stream) {
    const float* tok    = (const float*)d_in[0];
    const int*   wmask  = (const int*)d_in[1];
    const float* labe   = (const float*)d_in[3];
    const float* W_tok  = (const float*)d_in[4];
    const float* b_tok  = (const float*)d_in[5];
    const float* W_lab  = (const float*)d_in[6];
    const float* b_lab  = (const float*)d_in[7];
    const float* W1     = (const float*)d_in[8];
    const float* b1     = (const float*)d_in[9];
    const float* W2     = (const float*)d_in[10];
    const float* b2     = (const float*)d_in[11];
    float* out = (float*)d_out;

    const int L  = in_sizes[1];
    const int Wd = out_size / (Cn * 3);   // 1024

    char* ws = (char*)d_ws;
    size_t off = 0;
    auto alloc = [&](size_t bytes) { char* p = ws + off; off += (bytes + 255) & ~(size_t)255; return p; };
    int*   widx  = (int*)alloc(4096);
    float* tbuf  = (float*)alloc((size_t)Wd * H2 * 4);
    float* lbuf  = (float*)alloc((size_t)Cn * H2 * 4);
    float* Abuf  = (float*)alloc((size_t)Wd * Hd * 4);
    float* Bbuf  = (float*)alloc((size_t)Cn * Hd * 4);
    us* W1ct  = (us*)alloc((size_t)Hd * Hd * 2);
    us* W1cl  = (us*)alloc((size_t)Hd * Hd * 2);   // written, unused (hi-only P path)
    us* WtTh  = (us*)alloc((size_t)H2 * Hd * 2);
    us* WtTl  = (us*)alloc((size_t)H2 * Hd * 2);
    us* WlTh  = (us*)alloc((size_t)H2 * Hd * 2);
    us* WlTl  = (us*)alloc((size_t)H2 * Hd * 2);
    us* W1aTh = (us*)alloc((size_t)Hd * Hd * 2);
    us* W1aTl = (us*)alloc((size_t)Hd * Hd * 2);
    us* W1bTh = (us*)alloc((size_t)Hd * Hd * 2);
    us* W1bTl = (us*)alloc((size_t)Hd * Hd * 2);
    us* weh   = (us*)alloc((size_t)Wd * Hd * 2);
    us* wel   = (us*)alloc((size_t)Wd * Hd * 2);
    us* lah   = (us*)alloc((size_t)Cn * Hd * 2);
    us* lal   = (us*)alloc((size_t)Cn * Hd * 2);
    us* t0h   = (us*)alloc((size_t)Wd * Hd * 2);
    us* t0l   = (us*)alloc((size_t)Wd * Hd * 2);
    us* lb0h  = (us*)alloc((size_t)Cn * Hd * 2);
    us* lb0l  = (us*)alloc((size_t)Cn * Hd * 2);
    float* part = (float*)alloc((size_t)4 * Wd * Hd * 4);   // 12.6 MB arena (max slice set)

    // 1) init (widx, out<-b2) + scatter + we split
    k_init<<<(Wd * Cn * 3 + 255) / 256, 256, 0, stream>>>(widx, out, b2, Wd, Wd * Cn * 3);
    k_scatter<<<(L + 255) / 256, 256, 0, stream>>>(wmask, widx, L, Wd);
    k_build_we_split<<<(Wd * 192 + 255) / 256, 256, 0, stream>>>((const float4*)tok, widx, weh, wel, Wd);

    // 2) batched weight transpose+split (one launch)
    TSArgs ts;
    ts.src[0] = W_tok;  ts.th[0] = WtTh;  ts.tl[0] = WtTl;  ts.ld[0] = H2; ts.N[0] = H2;
    ts.src[1] = W_lab;  ts.th[1] = WlTh;  ts.tl[1] = WlTl;  ts.ld[1] = H2; ts.N[1] = H2;
    ts.src[2] = W1;                         ts.th[2] = W1aTh; ts.tl[2] = W1aTl; ts.ld[2] = Hd; ts.N[2] = Hd;
    ts.src[3] = W1 + (size_t)Hd * Hd;       ts.th[3] = W1bTh; ts.tl[3] = W1bTl; ts.ld[3] = Hd; ts.N[3] = Hd;
    ts.src[4] = W1 + (size_t)2 * Hd * Hd;   ts.th[4] = W1ct;  ts.tl[4] = W1cl;  ts.ld[4] = Hd; ts.N[4] = Hd;
    k_tsplit<<<dim3(H2 / 64, Hd / 64, 5), 256, 0, stream>>>(ts);

    // 3) label emb split
    k_split<<<(Cn * Hd / 4 + 255) / 256, 256, 0, stream>>>(labe, Hd, Hd, lah, lal, Cn * Hd / 4);

    // 4) t = we @ W_tok + b_tok  (1024x1536), K-split z=2 -> reduce (writes tbuf + t0 split)
    k_gemm2<<<dim3(H2 / 64, Wd / 64, 2), 256, 0, stream>>>(weh, wel, WtTh, WtTl, part, Wd, H2, Hd);
    k_reduce<<<(Wd * H2 + 255) / 256, 256, 0, stream>>>(part, 2, Wd * H2, H2, b_tok, tbuf, t0h, t0l, Hd);

    // 5) lb = labe @ W_lab + b_lab  (64x1536), z=8 -> reduce (writes lbuf + lb0 split)
    k_gemm2<<<dim3(H2 / 64, 1, 8), 256, 0, stream>>>(lah, lal, WlTh, WlTl, part, Cn, H2, Hd);
    k_reduce<<<(Cn * H2 + 255) / 256, 256, 0, stream>>>(part, 8, Cn * H2, H2, b_lab, lbuf, lb0h, lb0l, Hd);

    // 6) A = t0 @ W1a  (1024x768), z=4 -> reduce
    k_gemm2<<<dim3(Hd / 64, Wd / 64, 4), 256, 0, stream>>>(t0h, t0l, W1aTh, W1aTl, part, Wd, Hd, Hd);
    k_reduce<<<(Wd * Hd + 255) / 256, 256, 0, stream>>>(part, 4, Wd * Hd, Hd, nullptr, Abuf, nullptr, nullptr, 0);

    // 7) Bc = lb0 @ W1b + b1  (64x768), z=8 -> reduce
    k_gemm2<<<dim3(Hd / 64, 1, 8), 256, 0, stream>>>(lb0h, lb0l, W1bTh, W1bTl, part, Cn, Hd, Hd);
    k_reduce<<<(Cn * Hd + 255) / 256, 256, 0, stream>>>(part, 8, Cn * Hd, Hd, b1, Bbuf, nullptr, nullptr, 0);

    // 8) MFMA P-GEMM + fused epilogue (atomic into pre-biased out)
    k_mfma<<<dim3(Wd / 2, 3), 256, 0, stream>>>(tbuf, lbuf, W1ct, Abuf, Bbuf, W2, out);
}

// Round 5
// 372.002 us; speedup vs baseline: 1.7969x; 1.7939x over previous
//
#include <hip/hip_runtime.h>
#include <hip/hip_bf16.h>

static constexpr int Hd = 768;    // H
static constexpr int H2 = 1536;   // 2H
static constexpr int Cn = 64;     // C (labels)

typedef __attribute__((ext_vector_type(8))) short short8;
typedef __attribute__((ext_vector_type(4))) float f32x4;
typedef unsigned short us;

__device__ inline unsigned int f2bf2(float a, float b) {
    __hip_bfloat162 h = __float22bfloat162_rn(float2{a, b});
    return *reinterpret_cast<unsigned int*>(&h);
}

__device__ inline void split1(float x, us& h, us& l) {
    __hip_bfloat16 hb = __float2bfloat16(x);
    float hf = __bfloat162float(hb);
    __hip_bfloat16 lb_ = __float2bfloat16(x - hf);
    h = *reinterpret_cast<us*>(&hb);
    l = *reinterpret_cast<us*>(&lb_);
}

__device__ inline us f2b(float x) {
    __hip_bfloat16 b = __float2bfloat16(x);
    return *reinterpret_cast<us*>(&b);
}

__device__ inline float b2f(us u) {
    __hip_bfloat16 b = *reinterpret_cast<__hip_bfloat16*>(&u);
    return __bfloat162float(b);
}

__device__ inline void gload16(const void* g, void* l) {
    __builtin_amdgcn_global_load_lds(
        (const __attribute__((address_space(1))) unsigned int*)g,
        (__attribute__((address_space(3))) unsigned int*)l, 16, 0, 0);
}

// ---------------- init: widx = -1, out = broadcast b2 ----------------
__global__ void k_init(int* widx, float* out, const float* __restrict__ b2, int Wd, int outN) {
    int i = blockIdx.x * 256 + threadIdx.x;
    if (i < Wd) widx[i] = -1;
    if (i < outN) out[i] = b2[i % 3];
}

__global__ void k_scatter(const int* __restrict__ wmask, int* widx, int L, int Wd) {
    int i = blockIdx.x * 256 + threadIdx.x;
    if (i < L) {
        int m = wmask[i];
        if (m > 0 && m <= Wd) atomicMax(&widx[m - 1], i);  // last token wins
    }
}

// build we directly as hi/lo bf16 split
__global__ void k_build_we_split(const float4* __restrict__ tok, const int* __restrict__ widx,
                                 us* __restrict__ weh, us* __restrict__ wel, int Wd) {
    int i = blockIdx.x * 256 + threadIdx.x;   // over Wd * 192
    if (i >= Wd * 192) return;
    int w = i / 192, c4 = i - w * 192;
    int idx = widx[w];
    float4 v = (idx >= 0) ? tok[idx * 192 + c4] : float4{0.f, 0.f, 0.f, 0.f};
    us hh[4], ll[4];
    split1(v.x, hh[0], ll[0]);
    split1(v.y, hh[1], ll[1]);
    split1(v.z, hh[2], ll[2]);
    split1(v.w, hh[3], ll[3]);
    size_t o = (size_t)w * Hd + c4 * 4;
    *(ushort4*)&weh[o] = ushort4{hh[0], hh[1], hh[2], hh[3]};
    *(ushort4*)&wel[o] = ushort4{ll[0], ll[1], ll[2], ll[3]};
}

// ---------- batched transpose + hi/lo split: T[n][k] = split(W[k][n]) ----------
struct TSArgs {
    const float* src[5];
    us* th[5];
    us* tl[5];
    int ld[5];
    int N[5];
};
__global__ __launch_bounds__(256)
void k_tsplit(TSArgs a) {
    __shared__ float tile[64][65];
    const int z = blockIdx.z;
    const int n0 = blockIdx.x * 64, k0 = blockIdx.y * 64;
    if (n0 >= a.N[z]) return;
    const float* W = a.src[z];
    const int ld = a.ld[z];
    for (int idx = threadIdx.x; idx < 4096; idx += 256) {
        int kk = idx >> 6, nn = idx & 63;
        tile[kk][nn] = W[(size_t)(k0 + kk) * ld + n0 + nn];
    }
    __syncthreads();
    us* Th = a.th[z];
    us* Tl = a.tl[z];
    for (int idx = threadIdx.x; idx < 4096; idx += 256) {
        int nn = idx >> 6, kk = idx & 63;
        us h, l;
        split1(tile[kk][nn], h, l);
        size_t o = (size_t)(n0 + nn) * Hd + k0 + kk;
        Th[o] = h;
        Tl[o] = l;
    }
}

// ---------- row-major hi/lo split ----------
__global__ __launch_bounds__(256)
void k_split(const float* __restrict__ x, int lda, int cols,
             us* __restrict__ h, us* __restrict__ l, int n4) {
    int i = blockIdx.x * 256 + threadIdx.x;
    if (i >= n4) return;
    int c4 = cols >> 2;
    int row = i / c4, cc = (i - row * c4) * 4;
    float4 v = *(const float4*)&x[(size_t)row * lda + cc];
    us hh[4], ll[4];
    split1(v.x, hh[0], ll[0]);
    split1(v.y, hh[1], ll[1]);
    split1(v.z, hh[2], ll[2]);
    split1(v.w, hh[3], ll[3]);
    size_t o = (size_t)row * cols + cc;
    *(ushort4*)&h[o] = ushort4{hh[0], hh[1], hh[2], hh[3]};
    *(ushort4*)&l[o] = ushort4{ll[0], ll[1], ll[2], ll[3]};
}

// ---------- split-bf16 GEMM, LDS double-buffered, K-split partials ----------
__global__ __launch_bounds__(256)
void k_gemm2(const us* __restrict__ Ah, const us* __restrict__ Al,
             const us* __restrict__ BhT, const us* __restrict__ BlT,
             float* __restrict__ Cpart, int M, int N, int K) {
    __shared__ __align__(16) us S[2][4][64 * 32];
    const int tid = threadIdx.x, wave = tid >> 6, lane = tid & 63;
    const int quad = lane >> 4, l15 = lane & 15;
    const int wm = wave & 1, wn = wave >> 1;
    const int m0 = blockIdx.y * 64, n0 = blockIdx.x * 64;
    const int Ks = K / gridDim.z, kbeg = blockIdx.z * Ks, kend = kbeg + Ks;
    float* C = Cpart + (size_t)blockIdx.z * M * N;

    const int srow = wave * 16 + (lane >> 2), soff = (lane & 3) * 8;
    const size_t gaB = (size_t)(m0 + srow) * K + soff;
    const size_t gbB = (size_t)(n0 + srow) * K + soff;
    const int lo = wave * 16 * 32;

    f32x4 acc[2][2];
#pragma unroll
    for (int a = 0; a < 2; ++a)
#pragma unroll
        for (int b = 0; b < 2; ++b) acc[a][b] = (f32x4){0.f, 0.f, 0.f, 0.f};

    auto stage = [&](int p, int k0) {
        gload16(Ah + gaB + k0, &S[p][0][lo]);
        gload16(Al + gaB + k0, &S[p][1][lo]);
        gload16(BhT + gbB + k0, &S[p][2][lo]);
        gload16(BlT + gbB + k0, &S[p][3][lo]);
    };

    int p = 0;
    stage(0, kbeg);
    for (int k0 = kbeg; k0 < kend; k0 += 32) {
        __syncthreads();
        if (k0 + 32 < kend) stage(p ^ 1, k0 + 32);
        short8 ah[2], al[2], bh[2], bl[2];
#pragma unroll
        for (int mt = 0; mt < 2; ++mt) {
            int off = (wm * 32 + mt * 16 + l15) * 32 + quad * 8;
            ah[mt] = *(const short8*)&S[p][0][off];
            al[mt] = *(const short8*)&S[p][1][off];
        }
#pragma unroll
        for (int nt = 0; nt < 2; ++nt) {
            int off = (wn * 32 + nt * 16 + l15) * 32 + quad * 8;
            bh[nt] = *(const short8*)&S[p][2][off];
            bl[nt] = *(const short8*)&S[p][3][off];
        }
#pragma unroll
        for (int mt = 0; mt < 2; ++mt)
#pragma unroll
            for (int nt = 0; nt < 2; ++nt) {
                acc[mt][nt] = __builtin_amdgcn_mfma_f32_16x16x32_bf16(al[mt], bh[nt], acc[mt][nt], 0, 0, 0);
                acc[mt][nt] = __builtin_amdgcn_mfma_f32_16x16x32_bf16(ah[mt], bl[nt], acc[mt][nt], 0, 0, 0);
                acc[mt][nt] = __builtin_amdgcn_mfma_f32_16x16x32_bf16(ah[mt], bh[nt], acc[mt][nt], 0, 0, 0);
            }
        p ^= 1;
    }
#pragma unroll
    for (int mt = 0; mt < 2; ++mt)
#pragma unroll
        for (int nt = 0; nt < 2; ++nt) {
            int col = n0 + wn * 32 + nt * 16 + l15;
#pragma unroll
            for (int reg = 0; reg < 4; ++reg) {
                int row = m0 + wm * 32 + mt * 16 + quad * 4 + reg;
                C[(size_t)row * N + col] = acc[mt][nt][reg];
            }
        }
}

// ---------- reduce partials + bias; f32 out + hi/lo split (cols<scols) + plain bf16 (cols>=scols) ----
__global__ __launch_bounds__(256)
void k_reduce(const float* __restrict__ part, int S, int MN, int N,
              const float* __restrict__ bias, float* __restrict__ outF,
              us* __restrict__ sh, us* __restrict__ sl, int scols,
              us* __restrict__ bh) {
    int i = blockIdx.x * 256 + threadIdx.x;
    if (i >= MN) return;
    float v = 0.f;
    for (int s = 0; s < S; ++s) v += part[(size_t)s * MN + i];
    int row = i / N, col = i - row * N;
    if (bias) v += bias[col];
    if (outF) outF[i] = v;
    if (col < scols) {
        if (sh) {
            us h, l;
            split1(v, h, l);
            size_t o = (size_t)row * scols + col;
            sh[o] = h;
            sl[o] = l;
        }
    } else if (bh) {
        bh[(size_t)row * scols + (col - scols)] = f2b(v);
    }
}

// ---------- U build: U[cl][j][k] = bf16( lb1f[c,k] * f32(W1ct[j,k]) ) ----------
// phase covers c = phase*32 .. +31; grid = 32*768*96/256 = 9216 blocks exactly.
__global__ __launch_bounds__(256)
void k_ubuild(const us* __restrict__ W1ct, const float* __restrict__ lbuf,
              us* __restrict__ U, int phase) {
    int i = blockIdx.x * 256 + threadIdx.x;
    int k8 = i % 96;
    int j = (i / 96) % 768;
    int cl = i / (96 * 768);
    const int k = k8 * 8;
    short8 wv = *(const short8*)&W1ct[(size_t)j * Hd + k];
    const float* lp = &lbuf[(size_t)(phase * 32 + cl) * H2 + Hd + k];
    float4 l0 = *(const float4*)lp, l1 = *(const float4*)(lp + 4);
    float wf[8];
#pragma unroll
    for (int e = 0; e < 8; ++e) wf[e] = b2f((us)wv[e]);
    union { unsigned int u[4]; short8 s; } o;
    o.u[0] = f2bf2(wf[0] * l0.x, wf[1] * l0.y);
    o.u[1] = f2bf2(wf[2] * l0.z, wf[3] * l0.w);
    o.u[2] = f2bf2(wf[4] * l1.x, wf[5] * l1.y);
    o.u[3] = f2bf2(wf[6] * l1.z, wf[7] * l1.w);
    *(short8*)&U[((size_t)cl * Hd + j) * Hd + k] = o.s;
}

// ---------------- P-GEMM (m97-clone) + fused epilogue ----------------
// grid (6 jx, 8 my, 32 cz). Block: 128 w x 128 j at one c.
// P = t1b @ U_c^T; h = relu(P + Aw + Bc); scores partial -> atomicAdd out.
__global__ __launch_bounds__(256)
void k_mfma3(const us* __restrict__ Ab,   // t1b (1024,768) bf16
             const us* __restrict__ U,    // (32,768,768) bf16 [cl][j][k]
             const float* __restrict__ Aw,
             const float* __restrict__ Bc,
             const float* __restrict__ W2,
             float* __restrict__ out, int phase) {
    __shared__ __align__(16) us As[2][128 * 32];
    __shared__ __align__(16) us Bs[2][128 * 32];
    __shared__ float sred[128 * 3];
    const int tid = threadIdx.x, wave = tid >> 6, lane = tid & 63;
    const int quad = lane >> 4, l15 = lane & 15;
    const int wm = wave & 1, wn = wave >> 1;
    const int jt = blockIdx.x * 128, m0 = blockIdx.y * 128;
    const int c = phase * 32 + blockIdx.z;

    for (int i = tid; i < 128 * 3; i += 256) sred[i] = 0.f;

    const int srow = wave * 32 + (lane >> 2), soff = (lane & 3) * 8;
    const us* ga = Ab + (size_t)(m0 + srow) * Hd + soff;
    const us* gb = U + ((size_t)blockIdx.z * Hd + jt + srow) * Hd + soff;
    const int lo = (wave * 32) * 32;

    auto stage = [&](int p, int k0) {
        gload16(ga + k0, &As[p][lo]);
        gload16(ga + (size_t)16 * Hd + k0, &As[p][lo + 16 * 32]);
        gload16(gb + k0, &Bs[p][lo]);
        gload16(gb + (size_t)16 * Hd + k0, &Bs[p][lo + 16 * 32]);
    };

    f32x4 acc[4][4];
#pragma unroll
    for (int mt = 0; mt < 4; ++mt)
#pragma unroll
        for (int nt = 0; nt < 4; ++nt) acc[mt][nt] = (f32x4){0.f, 0.f, 0.f, 0.f};

    int p = 0;
    stage(0, 0);
    for (int k0 = 0; k0 < Hd; k0 += 32) {
        __syncthreads();
        if (k0 + 32 < Hd) stage(p ^ 1, k0 + 32);
        short8 af[4], bf[4];
#pragma unroll
        for (int mt = 0; mt < 4; ++mt)
            af[mt] = *(const short8*)&As[p][(wm * 64 + mt * 16 + l15) * 32 + quad * 8];
#pragma unroll
        for (int nt = 0; nt < 4; ++nt)
            bf[nt] = *(const short8*)&Bs[p][(wn * 64 + nt * 16 + l15) * 32 + quad * 8];
#pragma unroll
        for (int mt = 0; mt < 4; ++mt)
#pragma unroll
            for (int nt = 0; nt < 4; ++nt)
                acc[mt][nt] = __builtin_amdgcn_mfma_f32_16x16x32_bf16(
                    af[mt], bf[nt], acc[mt][nt], 0, 0, 0);
        p ^= 1;
    }

    // ---- epilogue ----
    float sacc[4][4][3];
#pragma unroll
    for (int a = 0; a < 4; ++a)
#pragma unroll
        for (int b = 0; b < 4; ++b)
#pragma unroll
            for (int r = 0; r < 3; ++r) sacc[a][b][r] = 0.f;
#pragma unroll
    for (int nt = 0; nt < 4; ++nt) {
        const int j = jt + wn * 64 + nt * 16 + l15;
        const float bc = Bc[(size_t)c * Hd + j];
        const float w20 = W2[j * 3 + 0], w21 = W2[j * 3 + 1], w22 = W2[j * 3 + 2];
#pragma unroll
        for (int mt = 0; mt < 4; ++mt)
#pragma unroll
            for (int reg = 0; reg < 4; ++reg) {
                const int w = m0 + wm * 64 + mt * 16 + quad * 4 + reg;
                float h = acc[mt][nt][reg] + Aw[(size_t)w * Hd + j] + bc;
                h = h > 0.f ? h : 0.f;
                sacc[mt][reg][0] += h * w20;
                sacc[mt][reg][1] += h * w21;
                sacc[mt][reg][2] += h * w22;
            }
    }
#pragma unroll
    for (int mt = 0; mt < 4; ++mt)
#pragma unroll
        for (int reg = 0; reg < 4; ++reg)
#pragma unroll
            for (int r = 0; r < 3; ++r) {
                float v = sacc[mt][reg][r];
                v += __shfl_xor(v, 1);
                v += __shfl_xor(v, 2);
                v += __shfl_xor(v, 4);
                v += __shfl_xor(v, 8);
                if (l15 == 0)
                    atomicAdd(&sred[(wm * 64 + mt * 16 + quad * 4 + reg) * 3 + r], v);
            }
    __syncthreads();
    for (int i = tid; i < 128 * 3; i += 256) {
        int w = m0 + i / 3, r = i - (i / 3) * 3;
        atomicAdd(&out[((size_t)w * Cn + c) * 3 + r], sred[i]);
    }
}

extern "C" void kernel_launch(void* const* d_in, const int* in_sizes, int n_in,
                              void* d_out, int out_size, void* d_ws, size_t ws_size,
                              hipStream_t stream) {
    const float* tok    = (const float*)d_in[0];
    const int*   wmask  = (const int*)d_in[1];
    const float* labe   = (const float*)d_in[3];
    const float* W_tok  = (const float*)d_in[4];
    const float* b_tok  = (const float*)d_in[5];
    const float* W_lab  = (const float*)d_in[6];
    const float* b_lab  = (const float*)d_in[7];
    const float* W1     = (const float*)d_in[8];
    const float* b1     = (const float*)d_in[9];
    const float* W2     = (const float*)d_in[10];
    const float* b2     = (const float*)d_in[11];
    float* out = (float*)d_out;

    const int L  = in_sizes[1];
    const int Wd = out_size / (Cn * 3);   // 1024

    char* ws = (char*)d_ws;
    size_t off = 0;
    auto alloc = [&](size_t bytes) { char* p = ws + off; off += (bytes + 255) & ~(size_t)255; return p; };
    // ---- persistent region ----
    int*   widx  = (int*)alloc(4096);
    float* tbuf  = (float*)alloc((size_t)Wd * H2 * 4);
    float* lbuf  = (float*)alloc((size_t)Cn * H2 * 4);
    float* Abuf  = (float*)alloc((size_t)Wd * Hd * 4);
    float* Bbuf  = (float*)alloc((size_t)Cn * Hd * 4);
    us* W1ct  = (us*)alloc((size_t)Hd * Hd * 2);
    us* W1cl  = (us*)alloc((size_t)Hd * Hd * 2);
    us* t1b   = (us*)alloc((size_t)Wd * Hd * 2);
    // ---- overlay region Q (dead after step 7); U aliases it ----
    size_t off_Q = off;
    us* WtTh  = (us*)alloc((size_t)H2 * Hd * 2);
    us* WtTl  = (us*)alloc((size_t)H2 * Hd * 2);
    us* WlTh  = (us*)alloc((size_t)H2 * Hd * 2);
    us* WlTl  = (us*)alloc((size_t)H2 * Hd * 2);
    us* W1aTh = (us*)alloc((size_t)Hd * Hd * 2);
    us* W1aTl = (us*)alloc((size_t)Hd * Hd * 2);
    us* W1bTh = (us*)alloc((size_t)Hd * Hd * 2);
    us* W1bTl = (us*)alloc((size_t)Hd * Hd * 2);
    us* weh   = (us*)alloc((size_t)Wd * Hd * 2);
    us* wel   = (us*)alloc((size_t)Wd * Hd * 2);
    us* lah   = (us*)alloc((size_t)Cn * Hd * 2);
    us* lal   = (us*)alloc((size_t)Cn * Hd * 2);
    us* t0h   = (us*)alloc((size_t)Wd * Hd * 2);
    us* t0l   = (us*)alloc((size_t)Wd * Hd * 2);
    us* lb0h  = (us*)alloc((size_t)Cn * Hd * 2);
    us* lb0l  = (us*)alloc((size_t)Cn * Hd * 2);
    float* part = (float*)alloc((size_t)4 * Wd * Hd * 4);
    us* U = (us*)(ws + off_Q);   // 32*768*768*2 = 37.75 MB, overlays Q after step 7

    // 1) init + scatter + we split
    k_init<<<(Wd * Cn * 3 + 255) / 256, 256, 0, stream>>>(widx, out, b2, Wd, Wd * Cn * 3);
    k_scatter<<<(L + 255) / 256, 256, 0, stream>>>(wmask, widx, L, Wd);
    k_build_we_split<<<(Wd * 192 + 255) / 256, 256, 0, stream>>>((const float4*)tok, widx, weh, wel, Wd);

    // 2) batched weight transpose+split
    TSArgs ts;
    ts.src[0] = W_tok;  ts.th[0] = WtTh;  ts.tl[0] = WtTl;  ts.ld[0] = H2; ts.N[0] = H2;
    ts.src[1] = W_lab;  ts.th[1] = WlTh;  ts.tl[1] = WlTl;  ts.ld[1] = H2; ts.N[1] = H2;
    ts.src[2] = W1;                         ts.th[2] = W1aTh; ts.tl[2] = W1aTl; ts.ld[2] = Hd; ts.N[2] = Hd;
    ts.src[3] = W1 + (size_t)Hd * Hd;       ts.th[3] = W1bTh; ts.tl[3] = W1bTl; ts.ld[3] = Hd; ts.N[3] = Hd;
    ts.src[4] = W1 + (size_t)2 * Hd * Hd;   ts.th[4] = W1ct;  ts.tl[4] = W1cl;  ts.ld[4] = Hd; ts.N[4] = Hd;
    k_tsplit<<<dim3(H2 / 64, Hd / 64, 5), 256, 0, stream>>>(ts);

    // 3) label emb split
    k_split<<<(Cn * Hd / 4 + 255) / 256, 256, 0, stream>>>(labe, Hd, Hd, lah, lal, Cn * Hd / 4);

    // 4) t = we @ W_tok + b_tok -> tbuf + t0 split + t1b bf16
    k_gemm2<<<dim3(H2 / 64, Wd / 64, 2), 256, 0, stream>>>(weh, wel, WtTh, WtTl, part, Wd, H2, Hd);
    k_reduce<<<(Wd * H2 + 255) / 256, 256, 0, stream>>>(part, 2, Wd * H2, H2, b_tok, tbuf, t0h, t0l, Hd, t1b);

    // 5) lb = labe @ W_lab + b_lab -> lbuf + lb0 split
    k_gemm2<<<dim3(H2 / 64, 1, 8), 256, 0, stream>>>(lah, lal, WlTh, WlTl, part, Cn, H2, Hd);
    k_reduce<<<(Cn * H2 + 255) / 256, 256, 0, stream>>>(part, 8, Cn * H2, H2, b_lab, lbuf, lb0h, lb0l, Hd, nullptr);

    // 6) Aw = t0 @ W1a
    k_gemm2<<<dim3(Hd / 64, Wd / 64, 4), 256, 0, stream>>>(t0h, t0l, W1aTh, W1aTl, part, Wd, Hd, Hd);
    k_reduce<<<(Wd * Hd + 255) / 256, 256, 0, stream>>>(part, 4, Wd * Hd, Hd, nullptr, Abuf, nullptr, nullptr, Hd, nullptr);

    // 7) Bc = lb0 @ W1b + b1
    k_gemm2<<<dim3(Hd / 64, 1, 8), 256, 0, stream>>>(lb0h, lb0l, W1bTh, W1bTl, part, Cn, Hd, Hd);
    k_reduce<<<(Cn * Hd + 255) / 256, 256, 0, stream>>>(part, 8, Cn * Hd, Hd, b1, Bbuf, nullptr, nullptr, Hd, nullptr);

    // 8) two c-phases: build U (overlays Q) then P-GEMM + fused epilogue
    for (int phase = 0; phase < 2; ++phase) {
        k_ubuild<<<9216, 256, 0, stream>>>(W1ct, lbuf, U, phase);
        k_mfma3<<<dim3(6, 8, 32), 256, 0, stream>>>(t1b, U, Abuf, Bbuf, W2, out, phase);
    }
}